// Round 8
// baseline (190.070 us; speedup 1.0000x reference)
//
#include <hip/hip_runtime.h>
#include <stdint.h>

// ---- types ----
typedef short s16x8 __attribute__((ext_vector_type(8)));
typedef float f32x4 __attribute__((ext_vector_type(4)));
typedef unsigned int u32x4 __attribute__((ext_vector_type(4)));

// log2(e) / sqrt(128): fold softmax scale + exp2 conversion into Q projection
#define QSCALE 0.12751743f

__device__ __forceinline__ unsigned short f2bf(float f) {
  unsigned int u = __builtin_bit_cast(unsigned int, f);
  u += 0x7fffu + ((u >> 16) & 1u);   // RNE
  return (unsigned short)(u >> 16);
}

__device__ __forceinline__ f32x4 mfma16(s16x8 a, s16x8 b, f32x4 c) {
  return __builtin_amdgcn_mfma_f32_16x16x32_bf16(a, b, c, 0, 0, 0);
}

// async global->LDS DMA, 16B/lane, dest = wave-uniform base + lane*16
#define GLD(GP, LP)                                                            \
  __builtin_amdgcn_global_load_lds(                                            \
      (const __attribute__((address_space(1))) unsigned int*)(GP),             \
      (__attribute__((address_space(3))) unsigned int*)(LP), 16, 0, 0)

// ============ kernel 1: weights fp32 -> bf16, K-chunk-tiled + swizzled ======
// Wt layout: [kc(32k)][n(384)][4 granules, col = gk ^ ((n>>1)&3)][8 elems]
__global__ __launch_bounds__(256) void wconv_k(const float* __restrict__ Wq,
                                               const float* __restrict__ Wk,
                                               const float* __restrict__ Wv,
                                               unsigned short* __restrict__ Wt) {
  int idx = (blockIdx.x * 256 + threadIdx.x) * 4;   // 393216 elems
  int tensor = idx >> 17;
  int r = idx & 131071;
  const float* src = tensor == 0 ? Wq : (tensor == 1 ? Wk : Wv);
  float4 f = *(const float4*)(src + r);
  float sc = (tensor == 0) ? QSCALE : 1.0f;
  ushort4 o;
  o.x = f2bf(f.x * sc); o.y = f2bf(f.y * sc);
  o.z = f2bf(f.z * sc); o.w = f2bf(f.w * sc);
  int nl = r >> 10, k = r & 1023;
  int n = tensor * 128 + nl;
  int kc = k >> 5, kl = k & 31, gk = kl >> 3, j = kl & 7;  // j in {0,4}
  int gks = gk ^ ((n >> 1) & 3);
  *(ushort4*)(Wt + kc * 12288 + (n * 4 + gks) * 8 + j) = o;
}

// ============ kernel 2: QKV projection GEMM (M=16384, N=384, K=1024) ========
// 512 blocks x 512 threads (8 waves), 32-row tiles, BK=32. Wave wv owns
// n-tiles wv*3..wv*3+2 over 2 m-tiles (6 MFMA/kc/wave). x+W DMA'd into dbuf
// LDS (swizzled, conflict-free). 56KB LDS -> 2 blocks/CU = 4 waves/SIMD.
__global__ __launch_bounds__(512, 4) void proj_k(const float* __restrict__ x,
    const float* __restrict__ bq, const float* __restrict__ bk,
    const float* __restrict__ bv, const unsigned short* __restrict__ Wt,
    unsigned short* __restrict__ Qg, unsigned short* __restrict__ KVg) {
  __shared__ unsigned int xb[2][1024];       // 2 x 4KB: x chunk [32r][8 gx swz] fp32
  __shared__ unsigned short wb[2][12288];    // 2 x 24KB: W chunk [384n][4 gk swz]
  const int tid = threadIdx.x;
  const int wv = tid >> 6, ln = tid & 15, quad = (tid >> 4) & 3;
  const int lane = tid & 63;
  const int mt = blockIdx.x;

  float bias[3];
  int tensor_[3], hcol_[3];
#pragma unroll
  for (int nt = 0; nt < 3; nt++) {
    int g_nt = wv * 3 + nt;
    int tensor = g_nt >> 3;
    int hcol = ((g_nt & 7) << 4) + ln;
    tensor_[nt] = tensor; hcol_[nt] = hcol;
    bias[nt] = (tensor == 0) ? bq[hcol] * QSCALE : (tensor == 1 ? bk[hcol] : bv[hcol]);
  }

  f32x4 acc[2][3];
  f32x4 zero = {0.f, 0.f, 0.f, 0.f};
#pragma unroll
  for (int m = 0; m < 2; m++)
#pragma unroll
    for (int nt = 0; nt < 3; nt++) acc[m][nt] = zero;

  // x DMA: waves 0-3 cover granules wv*64+lane (256 total); slot = r*8 + gx,
  // gx = (idx&7)^(r&7) baked at load. W DMA: 3 contiguous 1KB instrs/wave.
#define PJ_DMA(BUF, KC)                                                        \
  if (wv < 4) {                                                                \
    int idx = wv * 64 + lane;                                                  \
    int r_ = idx >> 3, gx = (idx & 7) ^ (r_ & 7);                              \
    GLD(x + (size_t)(mt * 32 + r_) * 1024 + (KC) * 32 + gx * 4,                \
        &xb[BUF][wv * 256]);                                                   \
  }                                                                            \
  _Pragma("unroll") for (int i = 0; i < 3; i++) {                              \
    GLD(Wt + (size_t)(KC) * 12288 + ((wv * 3 + i) * 64 + lane) * 8,            \
        &wb[BUF][(wv * 3 + i) * 512]);                                         \
  }

  PJ_DMA(0, 0);
  for (int kc = 0; kc < 32; kc++) {
    const int cur = kc & 1;
    __syncthreads();                 // DMA(cur) complete; prior reads done
    if (kc + 1 < 32) { PJ_DMA(cur ^ 1, kc + 1); }

    s16x8 a[2];
#pragma unroll
    for (int m = 0; m < 2; m++) {
      int r_ = m * 16 + ln;
      int c0 = (quad * 2) ^ (r_ & 7);
      int c1 = c0 ^ 1;
      f32x4 lo = *(const f32x4*)&xb[cur][(r_ * 8 + c0) * 4];
      f32x4 hi = *(const f32x4*)&xb[cur][(r_ * 8 + c1) * 4];
      u32x4 af;
      af.x = f2bf(lo.x) | ((unsigned)f2bf(lo.y) << 16);
      af.y = f2bf(lo.z) | ((unsigned)f2bf(lo.w) << 16);
      af.z = f2bf(hi.x) | ((unsigned)f2bf(hi.y) << 16);
      af.w = f2bf(hi.z) | ((unsigned)f2bf(hi.w) << 16);
      a[m] = __builtin_bit_cast(s16x8, af);
    }
#pragma unroll
    for (int nt = 0; nt < 3; nt++) {
      int n = (wv * 3 + nt) * 16 + ln;
      int gks = quad ^ ((n >> 1) & 3);
      s16x8 b = __builtin_bit_cast(s16x8, *(const u32x4*)&wb[cur][(n * 4 + gks) * 8]);
#pragma unroll
      for (int m = 0; m < 2; m++)
        acc[m][nt] = mfma16(a[m], b, acc[m][nt]);
    }
  }

  // epilogue: C-layout row = quad*4+reg, col = ln (m89-verified).
  // K tile elem (tr,h): (tr*16 + ghs)*8 + (h&7), ghs = (gh&8)|((gh&7)^(tr&7))
  // V tile elem (tr,h): 4096 + (h*4 + gts)*8 + (tr&7), gts = (tr>>3)^((h>>1)&3)
  const int r0 = mt * 32;
#pragma unroll
  for (int nt = 0; nt < 3; nt++) {
    int hcol = hcol_[nt];
#pragma unroll
    for (int m = 0; m < 2; m++) {
#pragma unroll
      for (int reg = 0; reg < 4; reg++) {
        float val = acc[m][nt][reg] + bias[nt];
        unsigned short h = f2bf(val);
        int rl = m * 16 + quad * 4 + reg;       // 0..31 == tr (32-row tiles)
        int t_abs = r0 + rl;
        size_t chbase = (size_t)((t_abs >> 12) * 128 + ((t_abs & 4095) >> 5)) * 8192;
        if (tensor_[nt] == 0) {
          Qg[(size_t)t_abs * 128 + hcol] = h;
        } else if (tensor_[nt] == 1) {
          int gh = hcol >> 3;
          int ghs = (gh & 8) | ((gh & 7) ^ (rl & 7));
          KVg[chbase + (rl * 16 + ghs) * 8 + (hcol & 7)] = h;
        } else {
          int gts = (rl >> 3) ^ ((hcol >> 1) & 3);
          KVg[chbase + 4096 + (hcol * 4 + gts) * 8 + (rl & 7)] = h;
        }
      }
    }
  }
}

// ============ kernel 3: causal attention, DMA-pipelined, no-max softmax =====
// BM=128 (8 waves x 16 rows), BN=32, seg=16 chunks, dense 576-block grid.
// Per chunk: one 16KB K/V tile DMA'd linearly (2 x 1KB per wave) into dbuf
// LDS; swizzled layouts -> conflict-free b128 fragment reads. One barrier per
// chunk. p = exp2(s); l via ones-B MFMA; bf16 partials.
__global__ __launch_bounds__(512, 4) void attn_k(const unsigned short* __restrict__ Qg,
    const unsigned short* __restrict__ KVg,
    unsigned short* __restrict__ Po, float* __restrict__ Plr) {
  __shared__ unsigned short kvb[2][8192];  // 2 x 16KB (K tile 8KB | V tile 8KB)
  __shared__ unsigned short Pl[128 * 40];  // 10KB, wave-private 16-row slabs
  const int tid = threadIdx.x;
  const int wv = tid >> 6, ln = tid & 15, quad = (tid >> 4) & 3;
  const int lane = tid & 63;
  const int id = blockIdx.x;               // dense slot, 0..575
  const int b = id / 144;
  int rem = id - b * 144;
  int a_ = 0;
  while (2 * (a_ + 1) * (a_ + 2) <= rem) a_++;       // <=7 scalar iters
  const int off = rem - 2 * a_ * (a_ + 1);
  const int qt = 4 * a_ + off / (a_ + 1);
  const int seg = off - (off / (a_ + 1)) * (a_ + 1);
  const int qbase = qt * 128;
  const int totch = 4 * qt + 4;
  const int nch = min(16, totch - seg * 16);

  const unsigned short* KVb = KVg + (size_t)b * 1048576;  // 128 chunks x 8192 elems

  // Q fragments: wave owns m-tile wv (16 rows); A-layout (m=ln, k=quad*8+j+32ks)
  const int qrow = b * 4096 + qbase + wv * 16 + ln;
  u32x4 qf[4];
#pragma unroll
  for (int ks = 0; ks < 4; ks++)
    qf[ks] = *(const u32x4*)((const char*)Qg + (size_t)qrow * 256 + ks * 64 + quad * 16);

  f32x4 o[8];
  f32x4 lacc;
  f32x4 zero = {0.f, 0.f, 0.f, 0.f};
  lacc = zero;
#pragma unroll
  for (int i = 0; i < 8; i++) o[i] = zero;
  const s16x8 onesb = {0x3F80, 0x3F80, 0x3F80, 0x3F80, 0x3F80, 0x3F80, 0x3F80, 0x3F80};

#define ATTN_DMA(BUF, CH)                                                      \
  _Pragma("unroll") for (int i = 0; i < 2; i++) {                              \
    GLD(KVb + (size_t)(CH) * 8192 + (wv * 2 + i) * 512 + lane * 8,             \
        &kvb[BUF][(wv * 2 + i) * 512]);                                        \
  }

  ATTN_DMA(0, seg * 16);
  for (int ci = 0; ci < nch; ci++) {
    const int cur = ci & 1;
    const int ch = seg * 16 + ci;
    const int t0 = ch * 32;
    __syncthreads();                 // DMA(cur) visible; prior reads of cur done
    if (ci + 1 < nch) { ATTN_DMA(cur ^ 1, ch + 1); }

    // S = Q K^T; K frag (t = nt*16+ln, granule gh = ks*4+quad, swizzled)
    f32x4 s[2];
#pragma unroll
    for (int nt = 0; nt < 2; nt++) s[nt] = zero;
#pragma unroll
    for (int ks = 0; ks < 4; ks++)
#pragma unroll
      for (int nt = 0; nt < 2; nt++) {
        int t = nt * 16 + ln;
        int gh = ks * 4 + quad;
        int ghs = (gh & 8) | ((gh & 7) ^ (t & 7));
        s16x8 kf = __builtin_bit_cast(s16x8, *(const u32x4*)&kvb[cur][(t * 16 + ghs) * 8]);
        s[nt] = mfma16(__builtin_bit_cast(s16x8, qf[ks]), kf, s[nt]);
      }

    // causal mask (chunks overlapping/beyond wave's rows; fully-masked -> p=0)
    if (t0 + 31 > qbase + wv * 16) {
#pragma unroll
      for (int nt = 0; nt < 2; nt++)
#pragma unroll
        for (int reg = 0; reg < 4; reg++) {
          int kidx = t0 + nt * 16 + ln;
          int qidx = qbase + wv * 16 + quad * 4 + reg;
          if (kidx > qidx) s[nt][reg] = -1e30f;
        }
    }

    // p = exp2(s) -> bf16 -> wave-private LDS (C->A layout round-trip)
#pragma unroll
    for (int nt = 0; nt < 2; nt++)
#pragma unroll
      for (int reg = 0; reg < 4; reg++) {
        float pv = __builtin_amdgcn_exp2f(s[nt][reg]);
        Pl[(wv * 16 + quad * 4 + reg) * 40 + nt * 16 + ln] = f2bf(pv);
      }

    // PV + l accumulation; V frag (h = nh*16+ln, granule gt = quad, swizzled)
    s16x8 pa = __builtin_bit_cast(s16x8,
        *(const u32x4*)&Pl[(wv * 16 + ln) * 40 + quad * 8]);
#pragma unroll
    for (int nh = 0; nh < 8; nh++) {
      int h = nh * 16 + ln;
      int gts = quad ^ ((h >> 1) & 3);
      s16x8 vf = __builtin_bit_cast(s16x8,
          *(const u32x4*)&kvb[cur][4096 + (h * 4 + gts) * 8]);
      o[nh] = mfma16(pa, vf, o[nh]);
    }
    lacc = mfma16(pa, onesb, lacc);
  }

  // epilogue: bf16 unnormalized partial + fp32 row sums
  unsigned short* po = Po + (size_t)id * 16384;
#pragma unroll
  for (int reg = 0; reg < 4; reg++) {
    int rowl = wv * 16 + quad * 4 + reg;
#pragma unroll
    for (int nh = 0; nh < 8; nh++)
      po[rowl * 128 + nh * 16 + ln] = f2bf(o[nh][reg]);
    if (ln == 0) Plr[id * 128 + rowl] = lacc[reg];
  }
}

// ============ kernel 4: combine bf16 partials (pure sums, coalesced) ========
__global__ __launch_bounds__(256) void combine_k(const unsigned short* __restrict__ Po,
    const float* __restrict__ Plr, float* __restrict__ out) {
  const int id = blockIdx.x;
  const int tileid = id >> 2, quarter = id & 3;
  const int qt = tileid & 31;
  const int b = tileid >> 5;
  const int a_ = qt >> 2, r_ = qt & 3;
  const int base = b * 144 + 2 * a_ * (a_ + 1) + r_ * (a_ + 1);
  const int nseg = a_ + 1;
  const int tid = threadIdx.x;
#pragma unroll
  for (int i = 0; i < 2; i++) {
    int g = quarter * 512 + i * 256 + tid;   // granule of 8 elems; 2048/tile
    int row = g >> 4;
    float acc[8] = {0.f, 0.f, 0.f, 0.f, 0.f, 0.f, 0.f, 0.f};
    float L = 0.f;
    for (int s = 0; s < nseg; s++) {
      u32x4 u = *(const u32x4*)(Po + (size_t)(base + s) * 16384 + g * 8);
      L += Plr[(base + s) * 128 + row];
      acc[0] += __builtin_bit_cast(float, u.x << 16);
      acc[1] += __builtin_bit_cast(float, u.x & 0xffff0000u);
      acc[2] += __builtin_bit_cast(float, u.y << 16);
      acc[3] += __builtin_bit_cast(float, u.y & 0xffff0000u);
      acc[4] += __builtin_bit_cast(float, u.z << 16);
      acc[5] += __builtin_bit_cast(float, u.z & 0xffff0000u);
      acc[6] += __builtin_bit_cast(float, u.w << 16);
      acc[7] += __builtin_bit_cast(float, u.w & 0xffff0000u);
    }
    float inv = 1.f / L;
    float* op = out + (size_t)tileid * 16384 + g * 8;
    f32x4 o0 = {acc[0] * inv, acc[1] * inv, acc[2] * inv, acc[3] * inv};
    f32x4 o1 = {acc[4] * inv, acc[5] * inv, acc[6] * inv, acc[7] * inv};
    *(f32x4*)op = o0;
    *(f32x4*)(op + 4) = o1;
  }
}

// ============ launch ============
extern "C" void kernel_launch(void* const* d_in, const int* in_sizes, int n_in,
                              void* d_out, int out_size, void* d_ws, size_t ws_size,
                              hipStream_t stream) {
  const float* x  = (const float*)d_in[0];
  const float* Wq = (const float*)d_in[1];
  const float* bq = (const float*)d_in[2];
  const float* Wk = (const float*)d_in[3];
  const float* bk = (const float*)d_in[4];
  const float* Wv = (const float*)d_in[5];
  const float* bv = (const float*)d_in[6];
  float* out = (float*)d_out;

  char* wsb = (char*)d_ws;
  unsigned short* Wt  = (unsigned short*)wsb;                 // 768 KB (tiled W)
  unsigned short* Qg  = (unsigned short*)(wsb + 786432);      // 4 MB
  unsigned short* KVg = (unsigned short*)(wsb + 4980736);     // 8 MB (512 x 16KB tiles)
  unsigned short* Po  = (unsigned short*)(wsb + 13369344);    // 18.9 MB (576 slots, bf16)
  float* Plr = (float*)(wsb + 32243712);                      // 288 KB

  wconv_k<<<dim3(384), dim3(256), 0, stream>>>(Wq, Wk, Wv, Wt);
  proj_k<<<dim3(512), dim3(512), 0, stream>>>(x, bq, bk, bv, Wt, Qg, KVg);
  attn_k<<<dim3(576), dim3(512), 0, stream>>>(Qg, KVg, Po, Plr);
  combine_k<<<dim3(512), dim3(256), 0, stream>>>(Po, Plr, out);
}